// Round 14
// baseline (91.970 us; speedup 1.0000x reference)
//
#include <hip/hip_runtime.h>

#define NN 50000
#define NE 800000
#define KF 256
#define HF 128
#define NEG 0.2f
#define INVLN2 1.44269504088896340736f

#define NB 391           // node buckets of 128 (v>>7)
#define EB 391           // edge blocks of 2048
#define EPB 2048         // edges per block
#define CAP 2432         // padded bucket capacity (mean 2048 + 8.5 sigma)
#define PREP_BLOCKS 64
#define PROJ_WAVES 3125  // NN/16
#define PH1 450          // proj blocks appended to k1
#define PH2 332          // proj blocks appended to k5 (450+332=782 -> 3128 waves)
#define HALF 25000       // NN/2: each agg wave owns nodes v and v+HALF

typedef __attribute__((ext_vector_type(8))) short bf16x8;
typedef __attribute__((ext_vector_type(4))) float f32x4;
typedef __attribute__((ext_vector_type(2))) float f32x2;

static __device__ __forceinline__ unsigned bf16_rne(float x) {
  unsigned u = __float_as_uint(x);
  return (u + 0x7fffu + ((u >> 16) & 1u)) >> 16;
}
static __device__ __forceinline__ unsigned cvt_pk(float lo, float hi) {
  unsigned r;
  asm("v_cvt_pk_bf16_f32 %0, %1, %2" : "=v"(r) : "v"(lo), "v"(hi));
  return r;
}
static __device__ __forceinline__ float exp2_raw(float x) {
  float r;
  asm("v_exp_f32 %0, %1" : "=v"(r) : "v"(x));
  return r;
}
// packed f32 math (CDNA2+ VOP3P): per-component IEEE identical to scalar ops
static __device__ __forceinline__ f32x2 pk_fma2(f32x2 a, f32x2 b, f32x2 c) {
  f32x2 r;
  asm("v_pk_fma_f32 %0, %1, %2, %3" : "=v"(r) : "v"(a), "v"(b), "v"(c));
  return r;
}
static __device__ __forceinline__ f32x2 pk_mul2(f32x2 a, f32x2 b) {
  f32x2 r;
  asm("v_pk_mul_f32 %0, %1, %2" : "=v"(r) : "v"(a), "v"(b));
  return r;
}
static __device__ __forceinline__ f32x2 pk_add2(f32x2 a, f32x2 b) {
  f32x2 r;
  asm("v_pk_add_f32 %0, %1, %2" : "=v"(r) : "v"(a), "v"(b));
  return r;
}

// ======== shared proj body: one wave projects 16 nodes (MFMA) + fused el/er ========
// ftp[n*64 + ct2*16 + l15] packs cols (ct2*32+l15, ct2*32+16+l15)
static __device__ __forceinline__ void proj_wave(
    const float* __restrict__ feat, const unsigned* __restrict__ wfcb,
    unsigned* __restrict__ ftp, const float* __restrict__ al,
    const float* __restrict__ ar, float* __restrict__ el, float* __restrict__ er,
    int wid, int lane) {
  if (wid >= PROJ_WAVES) return;
  const int m0 = wid * 16;
  const int row = m0 + (lane & 15);
  const int kb = (lane >> 4) * 8;

  f32x4 acc[8];
#pragma unroll
  for (int ct = 0; ct < 8; ct++) acc[ct] = (f32x4){0.f, 0.f, 0.f, 0.f};

  const float4* a4p = (const float4*)(feat + row * KF + kb);
#pragma unroll
  for (int ks = 0; ks < 8; ks++) {
    float4 a0 = a4p[ks * 8];
    float4 a1 = a4p[ks * 8 + 1];
    union { int4 i; bf16x8 s; } ua;
    ua.i = make_int4((int)cvt_pk(a0.x, a0.y), (int)cvt_pk(a0.z, a0.w),
                     (int)cvt_pk(a1.x, a1.y), (int)cvt_pk(a1.z, a1.w));
    bf16x8 af = ua.s;
#pragma unroll
    for (int ct = 0; ct < 8; ct++) {
      union { int4 i; bf16x8 s; } ub;
      ub.i = *(const int4*)&wfcb[((ks * 8 + ct) * 64 + lane) * 4];
      acc[ct] = __builtin_amdgcn_mfma_f32_16x16x32_bf16(af, ub.s, acc[ct], 0, 0, 0);
    }
  }

  const int rbase = m0 + (lane >> 4) * 4;
  const int l15 = lane & 15;
  float alv0[4], alv1[4], arv0[4], arv1[4];
#pragma unroll
  for (int t2 = 0; t2 < 4; t2++) {
    alv0[t2] = al[t2 * 32 + l15];
    alv1[t2] = al[t2 * 32 + 16 + l15];
    arv0[t2] = ar[t2 * 32 + l15];
    arv1[t2] = ar[t2 * 32 + 16 + l15];
  }
  float pl_[4][4], pr_[4][4];  // [r][head]
#pragma unroll
  for (int ct2 = 0; ct2 < 4; ct2++) {
#pragma unroll
    for (int r = 0; r < 4; r++) {
      unsigned wv = cvt_pk(acc[2 * ct2][r], acc[2 * ct2 + 1][r]);
      ftp[(rbase + r) * 64 + ct2 * 16 + l15] = wv;
      float f0 = __uint_as_float(wv << 16);
      float f1 = __uint_as_float(wv & 0xffff0000u);
      pl_[r][ct2] = f0 * alv0[ct2] + f1 * alv1[ct2];
      pr_[r][ct2] = f0 * arv0[ct2] + f1 * arv1[ct2];
    }
  }
#pragma unroll
  for (int o = 1; o < 16; o <<= 1) {
#pragma unroll
    for (int r = 0; r < 4; r++) {
#pragma unroll
      for (int hh = 0; hh < 4; hh++) {
        pl_[r][hh] += __shfl_xor(pl_[r][hh], o, 64);
        pr_[r][hh] += __shfl_xor(pr_[r][hh], o, 64);
      }
    }
  }
  if (l15 == 0) {
#pragma unroll
    for (int r = 0; r < 4; r++) {
#pragma unroll
      for (int hh = 0; hh < 4; hh++) {
        el[(rbase + r) * 4 + hh] = pl_[r][hh] * INVLN2;
        er[(rbase + r) * 4 + hh] = pr_[r][hh] * INVLN2;
      }
    }
  }
}

// ======== K0: wfcb prep (64 blocks) + gCnt zero (block 64) ========
__global__ __launch_bounds__(256) void k0_prep(
    const float* __restrict__ Wfc, unsigned* __restrict__ wfcb,
    int* __restrict__ gCnt) {
  if (blockIdx.x == PREP_BLOCKS) {
    for (int b = threadIdx.x; b < NB; b += 256) gCnt[b] = 0;
    return;
  }
  int t = blockIdx.x * 256 + threadIdx.x;
  int e2 = t & 3;
  int l  = (t >> 2) & 63;
  int ct = (t >> 8) & 7;
  int ks = t >> 11;
  int j = ct * 16 + (l & 15);
  int k = ks * 32 + (l >> 4) * 8 + 2 * e2;
  unsigned lo = bf16_rne(Wfc[j * KF + k]);
  unsigned hi = bf16_rne(Wfc[j * KF + k + 1]);
  wfcb[t] = lo | (hi << 16);
}

// ======== K1: two-pass LDS hist + atomic bucket-range reserve + scatter (R6-proven),
//              co-scheduled with proj blocks (blocks EB..EB+PH1-1) ========
__global__ __launch_bounds__(256) void k1_sort_proj(
    const int* __restrict__ dst, const int* __restrict__ src,
    const float* __restrict__ ew, int* __restrict__ gCnt, int2* __restrict__ tmp,
    const float* __restrict__ feat, const unsigned* __restrict__ wfcb,
    unsigned* __restrict__ ftp, const float* __restrict__ al,
    const float* __restrict__ ar, float* __restrict__ el, float* __restrict__ er) {
  if (blockIdx.x >= EB) {  // proj part 1: waves 0 .. PH1*4-1
    int pidx = blockIdx.x - EB;
    proj_wave(feat, wfcb, ftp, al, ar, el, er,
              (pidx * 256 + (int)threadIdx.x) >> 6, threadIdx.x & 63);
    return;
  }
  __shared__ int hist[NB];
  __shared__ int sbase[NB];
  __shared__ int lcnt[NB];
  int t = threadIdx.x;
  int e = blockIdx.x;
  for (int b = t; b < NB; b += 256) {
    hist[b] = 0;
    lcnt[b] = 0;
  }
  __syncthreads();
  int base = e * EPB;
  int cnt = min(EPB, NE - base);
  for (int k = t; k < cnt; k += 256) {
    atomicAdd(&hist[dst[base + k] >> 7], 1);  // LDS atomic
  }
  __syncthreads();
  for (int b = t; b < NB; b += 256) {
    sbase[b] = atomicAdd(&gCnt[b], hist[b]);  // 391 global atomics/block: range reserve
  }
  __syncthreads();
  for (int k = t; k < cnt; k += 256) {
    int i = base + k;
    int d = dst[i];  // second read of this block's slice is L2-warm (R7 lesson)
    int r = atomicAdd(&lcnt[d >> 7], 1);  // LDS atomic rank within (block,bucket)
    int pos = (d >> 7) * CAP + sbase[d >> 7] + r;
    tmp[pos] = make_int2((int)((unsigned)src[i] | ((unsigned)d << 16)),
                         __float_as_int(ew[i]));
  }
}

// ======== K5: per-bucket CSR finalize from padded tmp (blocks 0..NB-1) + proj part 2 ========
__global__ __launch_bounds__(256) void k5_bucket_proj(
    const int2* __restrict__ tmp, const int* __restrict__ gCnt,
    int* __restrict__ segbeg, int* __restrict__ segend, int2* __restrict__ es8,
    const float* __restrict__ feat, const unsigned* __restrict__ wfcb,
    unsigned* __restrict__ ftp, const float* __restrict__ al,
    const float* __restrict__ ar, float* __restrict__ el, float* __restrict__ er) {
  if (blockIdx.x >= NB) {  // proj part 2: waves PH1*4 .. PH1*4+PH2*4-1
    int pidx = (blockIdx.x - NB) + PH1;
    proj_wave(feat, wfcb, ftp, al, ar, el, er,
              (pidx * 256 + (int)threadIdx.x) >> 6, threadIdx.x & 63);
    return;
  }
  int b = blockIdx.x;
  int ebase = b * CAP;
  int eend = ebase + gCnt[b];
  int vbase = b * 128;
  __shared__ int cnt[128], buf[128], cur[128];
  int t = threadIdx.x;
  if (t < 128) cnt[t] = 0;
  __syncthreads();
  for (int i = ebase + t; i < eend; i += 256) {
    unsigned x = (unsigned)tmp[i].x;
    atomicAdd(&cnt[(x >> 16) & 127], 1);  // LDS atomic
  }
  __syncthreads();
  if (t < 128) buf[t] = cnt[t];
  __syncthreads();
  for (int o = 1; o < 128; o <<= 1) {
    int x = (t < 128 && t >= o) ? buf[t - o] : 0;
    __syncthreads();
    if (t < 128) buf[t] += x;
    __syncthreads();
  }
  if (t < 128) {
    cur[t] = buf[t] - cnt[t];  // exclusive
    int v = vbase + t;
    if (v < NN) {
      segbeg[v] = ebase + cur[t];
      segend[v] = ebase + buf[t];
    }
  }
  __syncthreads();
  for (int i = ebase + t; i < eend; i += 256) {
    int2 rec = tmp[i];
    unsigned x = (unsigned)rec.x;
    int r = atomicAdd(&cur[(x >> 16) & 127], 1);  // LDS atomic
    es8[ebase + r] = make_int2((int)(x & 0xFFFFu), rec.y);
  }
}

// ======== K6: fused softmax + aggregation: ONE WAVE = TWO INDEPENDENT NODES,
//              packed-f32 EDGE math (v_pk_*), no per-edge readfirstlane on w ========
// Per-node arithmetic identical per-component to R13 -> bitwise-identical output.
// lane owns cols c0 = (lane>>4)*32 + (lane&15), c1 = c0+16; head h = lane>>4
__global__ __launch_bounds__(256, 8) void agg_kernel(
    const unsigned* __restrict__ ftp, const float* __restrict__ el,
    const float* __restrict__ er, const int2* __restrict__ es8,
    const int* __restrict__ segbeg, const int* __restrict__ segend,
    const float* __restrict__ We, const float* __restrict__ bias,
    float* __restrict__ out) {
  int wid = (blockIdx.x * blockDim.x + threadIdx.x) >> 6;
  if (wid >= HALF) return;
  const int lane = threadIdx.x & 63;
  const int h = lane >> 4;
  const int c0 = h * 32 + (lane & 15), c1 = c0 + 16;
  f32x2 wxy2;
  wxy2[0] = We[c0] * INVLN2;
  wxy2[1] = We[c1] * INVLN2;
  f32x2 negv2;
  negv2[0] = NEG;
  negv2[1] = NEG;
  const float bx = bias[c0], by = bias[c1];

  const int vA = wid, vB = wid + HALF;
  int iA = __builtin_amdgcn_readfirstlane(segbeg[vA]);
  int eA = __builtin_amdgcn_readfirstlane(segend[vA]);
  int iB = __builtin_amdgcn_readfirstlane(segbeg[vB]);
  int eB = __builtin_amdgcn_readfirstlane(segend[vB]);
  const bool hasA = iA < eA, hasB = iB < eB;
  const float ervA = er[vA * 4 + h];  // log2 units
  const float ervB = er[vB * 4 + h];
  f32x2 nA = (f32x2){0.f, 0.f}, dA = (f32x2){0.f, 0.f};
  f32x2 nB = (f32x2){0.f, 0.f}, dB = (f32x2){0.f, 0.f};

  // w_ is wave-uniform VGPR (no rfl); packed pair ops cover both columns at once.
#define EDGE(w_, u_, e_, erv_, n_, d_)                              \
  {                                                                 \
    f32x2 bb;                                                       \
    bb[0] = (e_) + (erv_);                                          \
    bb[1] = bb[0];                                                  \
    f32x2 ww;                                                       \
    ww[0] = (w_);                                                   \
    ww[1] = (w_);                                                   \
    f32x2 t = pk_fma2(ww, wxy2, bb);                                \
    f32x2 tn = pk_mul2(t, negv2);                                   \
    t[0] = fmaxf(t[0], tn[0]);                                      \
    t[1] = fmaxf(t[1], tn[1]);                                      \
    f32x2 x;                                                        \
    x[0] = exp2_raw(t[0]);                                          \
    x[1] = exp2_raw(t[1]);                                          \
    f32x2 f;                                                        \
    f[0] = __uint_as_float((u_) << 16);                             \
    f[1] = __uint_as_float((u_) & 0xffff0000u);                     \
    n_ = pk_fma2(f, x, n_);                                         \
    d_ = pk_add2(d_, x);                                            \
  }

#define CHUNK8(i_, erv_, n_, d_)                                                     \
  {                                                                                  \
    int2 q0 = es8[i_],       q1 = es8[(i_) + 1], q2 = es8[(i_) + 2],                 \
         q3 = es8[(i_) + 3], q4 = es8[(i_) + 4], q5 = es8[(i_) + 5],                 \
         q6 = es8[(i_) + 6], q7 = es8[(i_) + 7];                                     \
    int s0 = __builtin_amdgcn_readfirstlane(q0.x);                                   \
    int s1 = __builtin_amdgcn_readfirstlane(q1.x);                                   \
    int s2 = __builtin_amdgcn_readfirstlane(q2.x);                                   \
    int s3 = __builtin_amdgcn_readfirstlane(q3.x);                                   \
    int s4 = __builtin_amdgcn_readfirstlane(q4.x);                                   \
    int s5 = __builtin_amdgcn_readfirstlane(q5.x);                                   \
    int s6 = __builtin_amdgcn_readfirstlane(q6.x);                                   \
    int s7 = __builtin_amdgcn_readfirstlane(q7.x);                                   \
    unsigned u0 = ftp[s0 * 64 + lane], u1 = ftp[s1 * 64 + lane];                     \
    unsigned u2 = ftp[s2 * 64 + lane], u3 = ftp[s3 * 64 + lane];                     \
    unsigned u4 = ftp[s4 * 64 + lane], u5 = ftp[s5 * 64 + lane];                     \
    unsigned u6 = ftp[s6 * 64 + lane], u7 = ftp[s7 * 64 + lane];                     \
    float e0 = el[s0 * 4 + h], e1 = el[s1 * 4 + h];                                  \
    float e2 = el[s2 * 4 + h], e3 = el[s3 * 4 + h];                                  \
    float e4 = el[s4 * 4 + h], e5 = el[s5 * 4 + h];                                  \
    float e6 = el[s6 * 4 + h], e7 = el[s7 * 4 + h];                                  \
    float w0 = __uint_as_float(q0.y), w1 = __uint_as_float(q1.y);                    \
    float w2 = __uint_as_float(q2.y), w3 = __uint_as_float(q3.y);                    \
    float w4 = __uint_as_float(q4.y), w5 = __uint_as_float(q5.y);                    \
    float w6 = __uint_as_float(q6.y), w7 = __uint_as_float(q7.y);                    \
    EDGE(w0, u0, e0, erv_, n_, d_);                                                  \
    EDGE(w1, u1, e1, erv_, n_, d_);                                                  \
    EDGE(w2, u2, e2, erv_, n_, d_);                                                  \
    EDGE(w3, u3, e3, erv_, n_, d_);                                                  \
    EDGE(w4, u4, e4, erv_, n_, d_);                                                  \
    EDGE(w5, u5, e5, erv_, n_, d_);                                                  \
    EDGE(w6, u6, e6, erv_, n_, d_);                                                  \
    EDGE(w7, u7, e7, erv_, n_, d_);                                                  \
    (i_) += 8;                                                                       \
  }

  // dual phase: alternate independent streams (B math hides A gathers, vice versa)
  while (iA + 8 <= eA && iB + 8 <= eB) {
    CHUNK8(iA, ervA, nA, dA);
    CHUNK8(iB, ervB, nB, dB);
  }
  // drain phases
  while (iA + 8 <= eA) CHUNK8(iA, ervA, nA, dA);
  while (iB + 8 <= eB) CHUNK8(iB, ervB, nB, dB);
  for (; iA < eA; iA++) {
    int2 q = es8[iA];
    int s = __builtin_amdgcn_readfirstlane(q.x);
    unsigned u = ftp[s * 64 + lane];
    float ee = el[s * 4 + h];
    float w = __uint_as_float(q.y);
    EDGE(w, u, ee, ervA, nA, dA);
  }
  for (; iB < eB; iB++) {
    int2 q = es8[iB];
    int s = __builtin_amdgcn_readfirstlane(q.x);
    unsigned u = ftp[s * 64 + lane];
    float ee = el[s * 4 + h];
    float w = __uint_as_float(q.y);
    EDGE(w, u, ee, ervB, nB, dB);
  }
#undef EDGE
#undef CHUNK8

  out[vA * HF + c0] = hasA ? nA[0] / dA[0] + bx : bx;
  out[vA * HF + c1] = hasA ? nA[1] / dA[1] + by : by;
  out[vB * HF + c0] = hasB ? nB[0] / dB[0] + bx : bx;
  out[vB * HF + c1] = hasB ? nB[1] / dB[1] + by : by;
}

extern "C" void kernel_launch(void* const* d_in, const int* in_sizes, int n_in,
                              void* d_out, int out_size, void* d_ws, size_t ws_size,
                              hipStream_t stream) {
  const float* feat = (const float*)d_in[0];
  const float* ew   = (const float*)d_in[1];
  const int*   src  = (const int*)d_in[2];
  const int*   dst  = (const int*)d_in[3];
  const float* Wfc  = (const float*)d_in[4];
  const float* We   = (const float*)d_in[5];
  const float* al   = (const float*)d_in[6];
  const float* ar   = (const float*)d_in[7];
  const float* bias = (const float*)d_in[8];
  float* out = (float*)d_out;

  char* ws = (char*)d_ws;
  unsigned* ftp        = (unsigned*)(ws + 0);          // 12,800,000
  float* el            = (float*)(ws + 12800000);      //    800,000
  float* er            = (float*)(ws + 13600000);      //    800,000
  int* segbeg          = (int*)(ws + 14400000);        //    200,000
  int* segend          = (int*)(ws + 14600000);        //    200,000
  int2* es8            = (int2*)(ws + 14800000);       //  7,607,296 (391*2432*8, padded)
  int2* tmp            = (int2*)(ws + 22407296);       //  7,607,296 (padded)
  int* gCnt            = (int*)(ws + 30014592);        //      1,564
  unsigned* wfcb       = (unsigned*)(ws + 30016160);   //     65,536 -> ~30.1 MB

  k0_prep<<<PREP_BLOCKS + 1, 256, 0, stream>>>(Wfc, wfcb, gCnt);
  k1_sort_proj<<<EB + PH1, 256, 0, stream>>>(dst, src, ew, gCnt, tmp, feat, wfcb, ftp,
                                             al, ar, el, er);
  k5_bucket_proj<<<NB + PH2, 256, 0, stream>>>(tmp, gCnt, segbeg, segend, es8, feat,
                                               wfcb, ftp, al, ar, el, er);
  agg_kernel<<<(HALF * 64) / 256, 256, 0, stream>>>(ftp, el, er, es8, segbeg, segend,
                                                    We, bias, out);
}

// Round 15
// 85.725 us; speedup vs baseline: 1.0729x; 1.0729x over previous
//
#include <hip/hip_runtime.h>

#define NN 50000
#define NE 800000
#define KF 256
#define HF 128
#define NEG 0.2f
#define INVLN2 1.44269504088896340736f

#define NB 391           // node buckets of 128 (v>>7)
#define EB 391           // edge blocks of 2048
#define EPB 2048         // edges per block
#define CAP 2432         // padded bucket capacity (mean 2048 + 8.5 sigma)
#define PREP_BLOCKS 64
#define PROJ_WAVES 3125  // NN/16
#define PH1 450          // proj blocks appended to k1
#define PH2 332          // proj blocks appended to k5 (450+332=782 -> 3128 waves)
#define HALF 25000       // NN/2: each agg wave owns nodes v and v+HALF

typedef __attribute__((ext_vector_type(8))) short bf16x8;
typedef __attribute__((ext_vector_type(4))) float f32x4;

static __device__ __forceinline__ unsigned bf16_rne(float x) {
  unsigned u = __float_as_uint(x);
  return (u + 0x7fffu + ((u >> 16) & 1u)) >> 16;
}
static __device__ __forceinline__ unsigned cvt_pk(float lo, float hi) {
  unsigned r;
  asm("v_cvt_pk_bf16_f32 %0, %1, %2" : "=v"(r) : "v"(lo), "v"(hi));
  return r;
}
static __device__ __forceinline__ float exp2_raw(float x) {
  float r;
  asm("v_exp_f32 %0, %1" : "=v"(r) : "v"(x));
  return r;
}

// ======== shared proj body: one wave projects 16 nodes (MFMA) + fused el/er ========
// ftp[n*64 + ct2*16 + l15] packs cols (ct2*32+l15, ct2*32+16+l15)
static __device__ __forceinline__ void proj_wave(
    const float* __restrict__ feat, const unsigned* __restrict__ wfcb,
    unsigned* __restrict__ ftp, const float* __restrict__ al,
    const float* __restrict__ ar, float* __restrict__ el, float* __restrict__ er,
    int wid, int lane) {
  if (wid >= PROJ_WAVES) return;
  const int m0 = wid * 16;
  const int row = m0 + (lane & 15);
  const int kb = (lane >> 4) * 8;

  f32x4 acc[8];
#pragma unroll
  for (int ct = 0; ct < 8; ct++) acc[ct] = (f32x4){0.f, 0.f, 0.f, 0.f};

  const float4* a4p = (const float4*)(feat + row * KF + kb);
#pragma unroll
  for (int ks = 0; ks < 8; ks++) {
    float4 a0 = a4p[ks * 8];
    float4 a1 = a4p[ks * 8 + 1];
    union { int4 i; bf16x8 s; } ua;
    ua.i = make_int4((int)cvt_pk(a0.x, a0.y), (int)cvt_pk(a0.z, a0.w),
                     (int)cvt_pk(a1.x, a1.y), (int)cvt_pk(a1.z, a1.w));
    bf16x8 af = ua.s;
#pragma unroll
    for (int ct = 0; ct < 8; ct++) {
      union { int4 i; bf16x8 s; } ub;
      ub.i = *(const int4*)&wfcb[((ks * 8 + ct) * 64 + lane) * 4];
      acc[ct] = __builtin_amdgcn_mfma_f32_16x16x32_bf16(af, ub.s, acc[ct], 0, 0, 0);
    }
  }

  const int rbase = m0 + (lane >> 4) * 4;
  const int l15 = lane & 15;
  float alv0[4], alv1[4], arv0[4], arv1[4];
#pragma unroll
  for (int t2 = 0; t2 < 4; t2++) {
    alv0[t2] = al[t2 * 32 + l15];
    alv1[t2] = al[t2 * 32 + 16 + l15];
    arv0[t2] = ar[t2 * 32 + l15];
    arv1[t2] = ar[t2 * 32 + 16 + l15];
  }
  float pl_[4][4], pr_[4][4];  // [r][head]
#pragma unroll
  for (int ct2 = 0; ct2 < 4; ct2++) {
#pragma unroll
    for (int r = 0; r < 4; r++) {
      unsigned wv = cvt_pk(acc[2 * ct2][r], acc[2 * ct2 + 1][r]);
      ftp[(rbase + r) * 64 + ct2 * 16 + l15] = wv;
      float f0 = __uint_as_float(wv << 16);
      float f1 = __uint_as_float(wv & 0xffff0000u);
      pl_[r][ct2] = f0 * alv0[ct2] + f1 * alv1[ct2];
      pr_[r][ct2] = f0 * arv0[ct2] + f1 * arv1[ct2];
    }
  }
#pragma unroll
  for (int o = 1; o < 16; o <<= 1) {
#pragma unroll
    for (int r = 0; r < 4; r++) {
#pragma unroll
      for (int hh = 0; hh < 4; hh++) {
        pl_[r][hh] += __shfl_xor(pl_[r][hh], o, 64);
        pr_[r][hh] += __shfl_xor(pr_[r][hh], o, 64);
      }
    }
  }
  if (l15 == 0) {
#pragma unroll
    for (int r = 0; r < 4; r++) {
#pragma unroll
      for (int hh = 0; hh < 4; hh++) {
        el[(rbase + r) * 4 + hh] = pl_[r][hh] * INVLN2;
        er[(rbase + r) * 4 + hh] = pr_[r][hh] * INVLN2;
      }
    }
  }
}

// ======== K0: wfcb prep (64 blocks) + gCnt zero (block 64) ========
__global__ __launch_bounds__(256) void k0_prep(
    const float* __restrict__ Wfc, unsigned* __restrict__ wfcb,
    int* __restrict__ gCnt) {
  if (blockIdx.x == PREP_BLOCKS) {
    for (int b = threadIdx.x; b < NB; b += 256) gCnt[b] = 0;
    return;
  }
  int t = blockIdx.x * 256 + threadIdx.x;
  int e2 = t & 3;
  int l  = (t >> 2) & 63;
  int ct = (t >> 8) & 7;
  int ks = t >> 11;
  int j = ct * 16 + (l & 15);
  int k = ks * 32 + (l >> 4) * 8 + 2 * e2;
  unsigned lo = bf16_rne(Wfc[j * KF + k]);
  unsigned hi = bf16_rne(Wfc[j * KF + k + 1]);
  wfcb[t] = lo | (hi << 16);
}

// ======== K1: two-pass LDS hist + atomic bucket-range reserve + scatter (R6-proven),
//              co-scheduled with proj blocks (blocks EB..EB+PH1-1) ========
__global__ __launch_bounds__(256) void k1_sort_proj(
    const int* __restrict__ dst, const int* __restrict__ src,
    const float* __restrict__ ew, int* __restrict__ gCnt, int2* __restrict__ tmp,
    const float* __restrict__ feat, const unsigned* __restrict__ wfcb,
    unsigned* __restrict__ ftp, const float* __restrict__ al,
    const float* __restrict__ ar, float* __restrict__ el, float* __restrict__ er) {
  if (blockIdx.x >= EB) {  // proj part 1: waves 0 .. PH1*4-1
    int pidx = blockIdx.x - EB;
    proj_wave(feat, wfcb, ftp, al, ar, el, er,
              (pidx * 256 + (int)threadIdx.x) >> 6, threadIdx.x & 63);
    return;
  }
  __shared__ int hist[NB];
  __shared__ int sbase[NB];
  __shared__ int lcnt[NB];
  int t = threadIdx.x;
  int e = blockIdx.x;
  for (int b = t; b < NB; b += 256) {
    hist[b] = 0;
    lcnt[b] = 0;
  }
  __syncthreads();
  int base = e * EPB;
  int cnt = min(EPB, NE - base);
  for (int k = t; k < cnt; k += 256) {
    atomicAdd(&hist[dst[base + k] >> 7], 1);  // LDS atomic
  }
  __syncthreads();
  for (int b = t; b < NB; b += 256) {
    sbase[b] = atomicAdd(&gCnt[b], hist[b]);  // 391 global atomics/block: range reserve
  }
  __syncthreads();
  for (int k = t; k < cnt; k += 256) {
    int i = base + k;
    int d = dst[i];  // second read of this block's slice is L2-warm (R7 lesson)
    int r = atomicAdd(&lcnt[d >> 7], 1);  // LDS atomic rank within (block,bucket)
    int pos = (d >> 7) * CAP + sbase[d >> 7] + r;
    tmp[pos] = make_int2((int)((unsigned)src[i] | ((unsigned)d << 16)),
                         __float_as_int(ew[i]));
  }
}

// ======== K5: per-bucket CSR finalize from padded tmp (blocks 0..NB-1) + proj part 2 ========
__global__ __launch_bounds__(256) void k5_bucket_proj(
    const int2* __restrict__ tmp, const int* __restrict__ gCnt,
    int* __restrict__ segbeg, int* __restrict__ segend, int2* __restrict__ es8,
    const float* __restrict__ feat, const unsigned* __restrict__ wfcb,
    unsigned* __restrict__ ftp, const float* __restrict__ al,
    const float* __restrict__ ar, float* __restrict__ el, float* __restrict__ er) {
  if (blockIdx.x >= NB) {  // proj part 2: waves PH1*4 .. PH1*4+PH2*4-1
    int pidx = (blockIdx.x - NB) + PH1;
    proj_wave(feat, wfcb, ftp, al, ar, el, er,
              (pidx * 256 + (int)threadIdx.x) >> 6, threadIdx.x & 63);
    return;
  }
  int b = blockIdx.x;
  int ebase = b * CAP;
  int eend = ebase + gCnt[b];
  int vbase = b * 128;
  __shared__ int cnt[128], buf[128], cur[128];
  int t = threadIdx.x;
  if (t < 128) cnt[t] = 0;
  __syncthreads();
  for (int i = ebase + t; i < eend; i += 256) {
    unsigned x = (unsigned)tmp[i].x;
    atomicAdd(&cnt[(x >> 16) & 127], 1);  // LDS atomic
  }
  __syncthreads();
  if (t < 128) buf[t] = cnt[t];
  __syncthreads();
  for (int o = 1; o < 128; o <<= 1) {
    int x = (t < 128 && t >= o) ? buf[t - o] : 0;
    __syncthreads();
    if (t < 128) buf[t] += x;
    __syncthreads();
  }
  if (t < 128) {
    cur[t] = buf[t] - cnt[t];  // exclusive
    int v = vbase + t;
    if (v < NN) {
      segbeg[v] = ebase + cur[t];
      segend[v] = ebase + buf[t];
    }
  }
  __syncthreads();
  for (int i = ebase + t; i < eend; i += 256) {
    int2 rec = tmp[i];
    unsigned x = (unsigned)rec.x;
    int r = atomicAdd(&cur[(x >> 16) & 127], 1);  // LDS atomic
    es8[ebase + r] = make_int2((int)(x & 0xFFFFu), rec.y);
  }
}

// ======== K6: fused softmax + aggregation: ONE WAVE = TWO INDEPENDENT NODES (R13),
//              single change vs R13: no per-edge readfirstlane on w (VGPR direct) ====
// Per-node arithmetic identical to R13 -> bitwise-identical output.
// lane owns cols c0 = (lane>>4)*32 + (lane&15), c1 = c0+16; head h = lane>>4
__global__ __launch_bounds__(256, 8) void agg_kernel(
    const unsigned* __restrict__ ftp, const float* __restrict__ el,
    const float* __restrict__ er, const int2* __restrict__ es8,
    const int* __restrict__ segbeg, const int* __restrict__ segend,
    const float* __restrict__ We, const float* __restrict__ bias,
    float* __restrict__ out) {
  int wid = (blockIdx.x * blockDim.x + threadIdx.x) >> 6;
  if (wid >= HALF) return;
  const int lane = threadIdx.x & 63;
  const int h = lane >> 4;
  const int c0 = h * 32 + (lane & 15), c1 = c0 + 16;
  const float wx = We[c0] * INVLN2, wy = We[c1] * INVLN2;
  const float bx = bias[c0], by = bias[c1];

  const int vA = wid, vB = wid + HALF;
  int iA = __builtin_amdgcn_readfirstlane(segbeg[vA]);
  int eA = __builtin_amdgcn_readfirstlane(segend[vA]);
  int iB = __builtin_amdgcn_readfirstlane(segbeg[vB]);
  int eB = __builtin_amdgcn_readfirstlane(segend[vB]);
  const bool hasA = iA < eA, hasB = iB < eB;
  const float ervA = er[vA * 4 + h];  // log2 units
  const float ervB = er[vB * 4 + h];
  float nA0 = 0.f, nA1 = 0.f, dA0 = 0.f, dA1 = 0.f;
  float nB0 = 0.f, nB1 = 0.f, dB0 = 0.f, dB1 = 0.f;

#define EDGE(w_, u_, e_, erv_, n0_, n1_, d0_, d1_)                  \
  {                                                                 \
    float base = (e_) + (erv_);                                     \
    float t0 = fmaf((w_), wx, base); t0 = fmaxf(t0, NEG * t0);      \
    float t1 = fmaf((w_), wy, base); t1 = fmaxf(t1, NEG * t1);      \
    float x0 = exp2_raw(t0), x1 = exp2_raw(t1);                     \
    float f0 = __uint_as_float((u_) << 16);                         \
    float f1 = __uint_as_float((u_) & 0xffff0000u);                 \
    n0_ = fmaf(f0, x0, n0_); d0_ += x0;                             \
    n1_ = fmaf(f1, x1, n1_); d1_ += x1;                             \
  }

#define CHUNK8(i_, erv_, n0_, n1_, d0_, d1_)                                         \
  {                                                                                  \
    int2 q0 = es8[i_],       q1 = es8[(i_) + 1], q2 = es8[(i_) + 2],                 \
         q3 = es8[(i_) + 3], q4 = es8[(i_) + 4], q5 = es8[(i_) + 5],                 \
         q6 = es8[(i_) + 6], q7 = es8[(i_) + 7];                                     \
    int s0 = __builtin_amdgcn_readfirstlane(q0.x);                                   \
    int s1 = __builtin_amdgcn_readfirstlane(q1.x);                                   \
    int s2 = __builtin_amdgcn_readfirstlane(q2.x);                                   \
    int s3 = __builtin_amdgcn_readfirstlane(q3.x);                                   \
    int s4 = __builtin_amdgcn_readfirstlane(q4.x);                                   \
    int s5 = __builtin_amdgcn_readfirstlane(q5.x);                                   \
    int s6 = __builtin_amdgcn_readfirstlane(q6.x);                                   \
    int s7 = __builtin_amdgcn_readfirstlane(q7.x);                                   \
    unsigned u0 = ftp[s0 * 64 + lane], u1 = ftp[s1 * 64 + lane];                     \
    unsigned u2 = ftp[s2 * 64 + lane], u3 = ftp[s3 * 64 + lane];                     \
    unsigned u4 = ftp[s4 * 64 + lane], u5 = ftp[s5 * 64 + lane];                     \
    unsigned u6 = ftp[s6 * 64 + lane], u7 = ftp[s7 * 64 + lane];                     \
    float e0 = el[s0 * 4 + h], e1 = el[s1 * 4 + h];                                  \
    float e2 = el[s2 * 4 + h], e3 = el[s3 * 4 + h];                                  \
    float e4 = el[s4 * 4 + h], e5 = el[s5 * 4 + h];                                  \
    float e6 = el[s6 * 4 + h], e7 = el[s7 * 4 + h];                                  \
    float w0 = __uint_as_float(q0.y), w1 = __uint_as_float(q1.y);                    \
    float w2 = __uint_as_float(q2.y), w3 = __uint_as_float(q3.y);                    \
    float w4 = __uint_as_float(q4.y), w5 = __uint_as_float(q5.y);                    \
    float w6 = __uint_as_float(q6.y), w7 = __uint_as_float(q7.y);                    \
    EDGE(w0, u0, e0, erv_, n0_, n1_, d0_, d1_);                                      \
    EDGE(w1, u1, e1, erv_, n0_, n1_, d0_, d1_);                                      \
    EDGE(w2, u2, e2, erv_, n0_, n1_, d0_, d1_);                                      \
    EDGE(w3, u3, e3, erv_, n0_, n1_, d0_, d1_);                                      \
    EDGE(w4, u4, e4, erv_, n0_, n1_, d0_, d1_);                                      \
    EDGE(w5, u5, e5, erv_, n0_, n1_, d0_, d1_);                                      \
    EDGE(w6, u6, e6, erv_, n0_, n1_, d0_, d1_);                                      \
    EDGE(w7, u7, e7, erv_, n0_, n1_, d0_, d1_);                                      \
    (i_) += 8;                                                                       \
  }

  // dual phase: alternate independent streams (B math hides A gathers, vice versa)
  while (iA + 8 <= eA && iB + 8 <= eB) {
    CHUNK8(iA, ervA, nA0, nA1, dA0, dA1);
    CHUNK8(iB, ervB, nB0, nB1, dB0, dB1);
  }
  // drain phases
  while (iA + 8 <= eA) CHUNK8(iA, ervA, nA0, nA1, dA0, dA1);
  while (iB + 8 <= eB) CHUNK8(iB, ervB, nB0, nB1, dB0, dB1);
  for (; iA < eA; iA++) {
    int2 q = es8[iA];
    int s = __builtin_amdgcn_readfirstlane(q.x);
    unsigned u = ftp[s * 64 + lane];
    float ee = el[s * 4 + h];
    float w = __uint_as_float(q.y);
    EDGE(w, u, ee, ervA, nA0, nA1, dA0, dA1);
  }
  for (; iB < eB; iB++) {
    int2 q = es8[iB];
    int s = __builtin_amdgcn_readfirstlane(q.x);
    unsigned u = ftp[s * 64 + lane];
    float ee = el[s * 4 + h];
    float w = __uint_as_float(q.y);
    EDGE(w, u, ee, ervB, nB0, nB1, dB0, dB1);
  }
#undef EDGE
#undef CHUNK8

  out[vA * HF + c0] = hasA ? nA0 / dA0 + bx : bx;
  out[vA * HF + c1] = hasA ? nA1 / dA1 + by : by;
  out[vB * HF + c0] = hasB ? nB0 / dB0 + bx : bx;
  out[vB * HF + c1] = hasB ? nB1 / dB1 + by : by;
}

extern "C" void kernel_launch(void* const* d_in, const int* in_sizes, int n_in,
                              void* d_out, int out_size, void* d_ws, size_t ws_size,
                              hipStream_t stream) {
  const float* feat = (const float*)d_in[0];
  const float* ew   = (const float*)d_in[1];
  const int*   src  = (const int*)d_in[2];
  const int*   dst  = (const int*)d_in[3];
  const float* Wfc  = (const float*)d_in[4];
  const float* We   = (const float*)d_in[5];
  const float* al   = (const float*)d_in[6];
  const float* ar   = (const float*)d_in[7];
  const float* bias = (const float*)d_in[8];
  float* out = (float*)d_out;

  char* ws = (char*)d_ws;
  unsigned* ftp        = (unsigned*)(ws + 0);          // 12,800,000
  float* el            = (float*)(ws + 12800000);      //    800,000
  float* er            = (float*)(ws + 13600000);      //    800,000
  int* segbeg          = (int*)(ws + 14400000);        //    200,000
  int* segend          = (int*)(ws + 14600000);        //    200,000
  int2* es8            = (int2*)(ws + 14800000);       //  7,607,296 (391*2432*8, padded)
  int2* tmp            = (int2*)(ws + 22407296);       //  7,607,296 (padded)
  int* gCnt            = (int*)(ws + 30014592);        //      1,564
  unsigned* wfcb       = (unsigned*)(ws + 30016160);   //     65,536 -> ~30.1 MB

  k0_prep<<<PREP_BLOCKS + 1, 256, 0, stream>>>(Wfc, wfcb, gCnt);
  k1_sort_proj<<<EB + PH1, 256, 0, stream>>>(dst, src, ew, gCnt, tmp, feat, wfcb, ftp,
                                             al, ar, el, er);
  k5_bucket_proj<<<NB + PH2, 256, 0, stream>>>(tmp, gCnt, segbeg, segend, es8, feat,
                                               wfcb, ftp, al, ar, el, er);
  agg_kernel<<<(HALF * 64) / 256, 256, 0, stream>>>(ftp, el, er, es8, segbeg, segend,
                                                    We, bias, out);
}